// Round 7
// baseline (160.029 us; speedup 1.0000x reference)
//
#include <hip/hip_runtime.h>

// SubtitleColorConsistencyLoss — MI355X (gfx950)
// R6: wave-per-span, channel-per-lane layout. No LDS, no barriers, no flush:
//     8 shuffles/span (vs 19), results go straight to the global table via
//     18 atomics/span (~590K total — R5's flush already proved 328K is cheap).

namespace {
constexpr int NIMG = 8;
constexpr int NCH  = 16;
constexpr int HWPX = 512 * 512;
constexpr int KSEG = 65;     // labels 0..64; slot 0 doubles as background stats
constexpr int NF   = 18;     // [0]=count [1]=sqsum [2..17]=channel sums
constexpr int NBLK = 256;    // blocks per image; 16 spans (1024 px) per block
constexpr float EPSV   = 1e-6f;
constexpr float MARGIN = 0.5f;
constexpr float LAMBDA = 0.4f;
constexpr float MINPIX = 20.0f;
}

__global__ __launch_bounds__(256) void accum_kernel(
    const float* __restrict__ color,
    const int*   __restrict__ labels,
    float* __restrict__ ws)
{
    const int n = blockIdx.y;
    const float* colN = color  + (size_t)n * NCH * HWPX;
    const int*   labN = labels + (size_t)n * HWPX;
    float*       wsN  = ws     + (size_t)n * KSEG * NF;

    const int wave = threadIdx.x >> 6;   // 0..3
    const int lane = threadIdx.x & 63;
    const int c    = lane >> 2;          // channel owned by this lane
    const int s    = lane & 3;           // quarter of the 64-px span

    #pragma unroll
    for (int i = 0; i < 4; ++i) {
        const int span = blockIdx.x * 16 + wave * 4 + i;   // 64-px span id
        const int p    = span * 64;

        const int lab  = labN[p + lane];                   // 256B coalesced
        const int lab0 = __builtin_amdgcn_readfirstlane(lab);

        if (__all(lab == lab0)) {
            // fast path: uniform span. Lane reads 16 floats of channel c:
            // float4s at indices k*4+s (k=0..3) -> 64B-contiguous per quad.
            const float* cb = colN + (size_t)c * HWPX + p + s * 4;
            const float4 v0 = *reinterpret_cast<const float4*>(cb);
            const float4 v1 = *reinterpret_cast<const float4*>(cb + 16);
            const float4 v2 = *reinterpret_cast<const float4*>(cb + 32);
            const float4 v3 = *reinterpret_cast<const float4*>(cb + 48);

            float fs = ((v0.x + v0.y) + (v0.z + v0.w))
                     + ((v1.x + v1.y) + (v1.z + v1.w))
                     + ((v2.x + v2.y) + (v2.z + v2.w))
                     + ((v3.x + v3.y) + (v3.z + v3.w));
            float sq = v0.x*v0.x + v0.y*v0.y + v0.z*v0.z + v0.w*v0.w
                     + v1.x*v1.x + v1.y*v1.y + v1.z*v1.z + v1.w*v1.w
                     + v2.x*v2.x + v2.y*v2.y + v2.z*v2.z + v2.w*v2.w
                     + v3.x*v3.x + v3.y*v3.y + v3.z*v3.z + v3.w*v3.w;

            // channel sum: reduce within the 4-lane quad (2 shuffles)
            fs += __shfl_xor(fs, 1);
            fs += __shfl_xor(fs, 2);
            // sqsum: full-wave reduce (6 shuffles)
            sq += __shfl_xor(sq, 1);
            sq += __shfl_xor(sq, 2);
            sq += __shfl_xor(sq, 4);
            sq += __shfl_xor(sq, 8);
            sq += __shfl_xor(sq, 16);
            sq += __shfl_xor(sq, 32);

            float* seg = wsN + lab0 * NF;
            if (s == 0) atomicAdd(seg + 2 + c, fs);   // 16 lanes, 16 addrs
            if (lane == 0) {
                atomicAdd(seg + 0, 64.0f);
                atomicAdd(seg + 1, sq);
            }
        } else {
            // correctness fallback (never taken on this data):
            // lane owns pixel p+lane, loops its 16 channels.
            float sqp = 0.0f;
            float* seg = wsN + lab * NF;
            for (int cc = 0; cc < NCH; ++cc) {
                const float x = colN[(size_t)cc * HWPX + p + lane];
                sqp += x * x;
                atomicAdd(seg + 2 + cc, x);
            }
            atomicAdd(seg + 0, 1.0f);
            atomicAdd(seg + 1, sqp);
        }
    }
}

__global__ __launch_bounds__(256) void finalize_kernel(
    const float* __restrict__ ws, float* __restrict__ out)
{
    __shared__ float mbg[NIMG][NCH];
    __shared__ float bgcnt[NIMG];
    __shared__ float r0[256], r1[256], r2[256];
    const int tid = threadIdx.x;
    if (tid < NIMG * NCH) {
        const int n = tid / NCH, c = tid % NCH;
        const float* b = ws + (size_t)n * KSEG * NF;   // slot 0 = background
        const float cnt = b[0];
        mbg[n][c] = b[2 + c] / (cnt + EPSV);
        if (c == 0) bgcnt[n] = cnt;
    }
    __syncthreads();

    float vsum = 0.0f, intraS = 0.0f, interS = 0.0f;
    for (int idx = tid; idx < NIMG * KSEG; idx += 256) {
        const int n = idx / KSEG, k = idx % KSEG;
        if (k == 0) continue;
        const float* s = ws + ((size_t)n * KSEG + k) * NF;
        const float cnt = s[0], sq = s[1];
        const float denom = cnt + EPSV;
        float d2 = 0.0f, msf = 0.0f, msm = 0.0f;
        #pragma unroll
        for (int c = 0; c < NCH; ++c) {
            const float f  = s[2 + c];
            const float mu = f / denom;
            msf += mu * f;
            msm += mu * mu;
            const float dd = mu - mbg[n][c];
            d2 += dd * dd;
        }
        const float intra = (sq - 2.0f * msf + cnt * msm) / denom;
        const float dist  = sqrtf(d2 + 1e-12f);
        const float t     = fmaxf(MARGIN - dist, 0.0f);
        const float inter = t * t;
        if ((cnt >= MINPIX) && (bgcnt[n] >= MINPIX)) {
            vsum += 1.0f; intraS += intra; interS += inter;
        }
    }
    r0[tid] = vsum; r1[tid] = intraS; r2[tid] = interS;
    __syncthreads();
    for (int sft = 128; sft; sft >>= 1) {
        if (tid < sft) {
            r0[tid] += r0[tid + sft];
            r1[tid] += r1[tid + sft];
            r2[tid] += r2[tid + sft];
        }
        __syncthreads();
    }
    if (tid == 0) {
        const float total = r0[0];
        const float safe  = fmaxf(total, 1.0f);
        out[0] = (total > 0.0f) ? (r1[0] + LAMBDA * r2[0]) / safe : 0.0f;
    }
}

extern "C" void kernel_launch(void* const* d_in, const int* in_sizes, int n_in,
                              void* d_out, int out_size, void* d_ws, size_t ws_size,
                              hipStream_t stream) {
    const float* color  = (const float*)d_in[0];
    const int*   labels = (const int*)d_in[2];
    float* ws  = (float*)d_ws;
    float* out = (float*)d_out;

    hipMemsetAsync(ws, 0, (size_t)NIMG * KSEG * NF * sizeof(float), stream);

    dim3 grid(NBLK, NIMG);   // 2048 blocks, 16 spans (1024 px) each
    accum_kernel<<<grid, 256, 0, stream>>>(color, labels, ws);
    finalize_kernel<<<1, 256, 0, stream>>>(ws, out);
}

// Round 8
// 43.041 us; speedup vs baseline: 3.7181x; 3.7181x over previous
//
#include <hip/hip_runtime.h>

// SubtitleColorConsistencyLoss — MI355X (gfx950)
// R7: decouple labels via span-compress pre-pass; color pass streams each
//     (n,c) plane contiguously (2048 blocks x 64KB sequential), span labels
//     preloaded+shfl-broadcast, tiny LDS table (65x2), sparse flush.
//     Atomic-cliff lessons (R3/R4/R6): no tickets, no dense global atomics.

namespace {
constexpr int NIMG = 8;
constexpr int NCH  = 16;
constexpr int HWPX = 512 * 512;
constexpr int KSEG = 65;                 // labels 0..64; slot 0 = background
constexpr int SPANS = HWPX / 64;         // 4096 spans per image
// ws layout (floats): [0,32768) span labels (int bitcast) |
// [WS_TAB, +TAB_SZ) per-(n,c,k){sum,sq} | [WS_CNT, +CNT_SZ) counts (n,k)
constexpr int WS_TAB = NIMG * SPANS;             // 32768
constexpr int TAB_SZ = NIMG * NCH * KSEG * 2;    // 16640
constexpr int WS_CNT = WS_TAB + TAB_SZ;
constexpr int CNT_SZ = NIMG * KSEG;              // 520
constexpr float EPSV   = 1e-6f;
constexpr float MARGIN = 0.5f;
constexpr float LAMBDA = 0.4f;
constexpr float MINPIX = 20.0f;
}

// Pass A: span-label compression. Uniform 64-px span -> its label, else -1.
__global__ __launch_bounds__(256) void spanlab_kernel(
    const int* __restrict__ labels, int* __restrict__ spanlab)
{
    const int n   = blockIdx.y;
    const int tid = threadIdx.x;
    const int grp = tid >> 4, l16 = tid & 15, wgrp = (tid & 63) >> 4;
    const int span = blockIdx.x * 16 + grp;
    const int p    = span * 64 + l16 * 4;

    const int4 lab = *reinterpret_cast<const int4*>(labels + (size_t)n * HWPX + p);
    const int  lab0 = __shfl(lab.x, 0, 16);
    const bool uni  = (lab.x == lab.y) && (lab.x == lab.z) &&
                      (lab.x == lab.w) && (lab.x == lab0);
    const unsigned long long b = __ballot((int)uni);
    const unsigned long long m = 0xFFFFull << (wgrp * 16);
    if (l16 == 0)
        spanlab[n * SPANS + span] = ((b & m) == m) ? lab0 : -1;
}

// Pass B: contiguous stream of one (n,c) plane chunk per block.
__global__ __launch_bounds__(256) void stream_kernel(
    const float* __restrict__ color,
    const int*   __restrict__ labels,
    const int*   __restrict__ spanlab,
    float* __restrict__ tab,
    float* __restrict__ cnt)
{
    const int plane = blockIdx.y;        // n*16 + c
    const int n = plane >> 4, c = plane & 15;
    const bool countPlane = (c == 0);

    __shared__ float ltab[KSEG * 2];
    __shared__ float lcnt[KSEG];
    const int tid = threadIdx.x;
    if (tid < KSEG * 2) ltab[tid] = 0.0f;
    if (tid < KSEG)     lcnt[tid] = 0.0f;

    const int grp = tid >> 4, l16 = tid & 15;
    const int spanBase = blockIdx.x * 256;   // 256 spans (16K px) per chunk
    // preload this group's 16 span labels (iter i -> lane i's value)
    const int labv = spanlab[n * SPANS + spanBase + l16 * 16 + grp];
    const float* colP = color + ((size_t)n * NCH + c) * HWPX;
    __syncthreads();

    for (int i = 0; i < 16; ++i) {
        const int span = spanBase + i * 16 + grp;
        const int p    = span * 64 + l16 * 4;
        const int slab = __shfl(labv, i, 16);
        const float4 v = *reinterpret_cast<const float4*>(colP + p);

        if (slab >= 0) {
            float fs = (v.x + v.y) + (v.z + v.w);
            float sq = v.x * v.x + v.y * v.y + v.z * v.z + v.w * v.w;
            fs += __shfl_xor(fs, 1, 16);  sq += __shfl_xor(sq, 1, 16);
            fs += __shfl_xor(fs, 2, 16);  sq += __shfl_xor(sq, 2, 16);
            fs += __shfl_xor(fs, 4, 16);  sq += __shfl_xor(sq, 4, 16);
            fs += __shfl_xor(fs, 8, 16);  sq += __shfl_xor(sq, 8, 16);
            if (l16 == 0) {
                atomicAdd(&ltab[slab * 2 + 0], fs);
                atomicAdd(&ltab[slab * 2 + 1], sq);
                if (countPlane) atomicAdd(&lcnt[slab], 64.0f);
            }
        } else {
            // non-uniform span fallback (never taken on this data)
            const int4 lb = *reinterpret_cast<const int4*>(
                labels + (size_t)n * HWPX + p);
            const float vv[4] = {v.x, v.y, v.z, v.w};
            const int   ll[4] = {lb.x, lb.y, lb.z, lb.w};
            #pragma unroll
            for (int j = 0; j < 4; ++j) {
                atomicAdd(&ltab[ll[j] * 2 + 0], vv[j]);
                atomicAdd(&ltab[ll[j] * 2 + 1], vv[j] * vv[j]);
                if (countPlane) atomicAdd(&lcnt[ll[j]], 1.0f);
            }
        }
    }

    __syncthreads();
    float* tabP = tab + (size_t)plane * KSEG * 2;
    for (int i = tid; i < KSEG * 2; i += 256) {
        const float x = ltab[i];
        if (x != 0.0f) atomicAdd(tabP + i, x);
    }
    if (countPlane) {
        float* cntP = cnt + (size_t)n * KSEG;
        for (int i = tid; i < KSEG; i += 256) {
            const float x = lcnt[i];
            if (x != 0.0f) atomicAdd(cntP + i, x);
        }
    }
}

__global__ __launch_bounds__(256) void finalize_kernel(
    const float* __restrict__ tab, const float* __restrict__ cnt,
    float* __restrict__ out)
{
    __shared__ float mbg[NIMG][NCH];
    __shared__ float bgcnt[NIMG];
    __shared__ float r0[256], r1[256], r2[256];
    const int tid = threadIdx.x;
    if (tid < NIMG * NCH) {
        const int n = tid / NCH, c = tid % NCH;
        const float cn = cnt[n * KSEG + 0];
        mbg[n][c] = tab[((size_t)(n * NCH + c) * KSEG + 0) * 2 + 0] / (cn + EPSV);
        if (c == 0) bgcnt[n] = cn;
    }
    __syncthreads();

    float vsum = 0.0f, intraS = 0.0f, interS = 0.0f;
    for (int idx = tid; idx < NIMG * KSEG; idx += 256) {
        const int n = idx / KSEG, k = idx % KSEG;
        if (k == 0) continue;
        const float cn = cnt[n * KSEG + k];
        const float denom = cn + EPSV;
        float sq = 0.0f, d2 = 0.0f, msf = 0.0f, msm = 0.0f;
        #pragma unroll
        for (int c = 0; c < NCH; ++c) {
            const float f  = tab[((size_t)(n * NCH + c) * KSEG + k) * 2 + 0];
            sq            += tab[((size_t)(n * NCH + c) * KSEG + k) * 2 + 1];
            const float mu = f / denom;
            msf += mu * f;
            msm += mu * mu;
            const float dd = mu - mbg[n][c];
            d2 += dd * dd;
        }
        const float intra = (sq - 2.0f * msf + cn * msm) / denom;
        const float dist  = sqrtf(d2 + 1e-12f);
        const float t     = fmaxf(MARGIN - dist, 0.0f);
        const float inter = t * t;
        if ((cn >= MINPIX) && (bgcnt[n] >= MINPIX)) {
            vsum += 1.0f; intraS += intra; interS += inter;
        }
    }
    r0[tid] = vsum; r1[tid] = intraS; r2[tid] = interS;
    __syncthreads();
    for (int sft = 128; sft; sft >>= 1) {
        if (tid < sft) {
            r0[tid] += r0[tid + sft];
            r1[tid] += r1[tid + sft];
            r2[tid] += r2[tid + sft];
        }
        __syncthreads();
    }
    if (tid == 0) {
        const float total = r0[0];
        const float safe  = fmaxf(total, 1.0f);
        out[0] = (total > 0.0f) ? (r1[0] + LAMBDA * r2[0]) / safe : 0.0f;
    }
}

extern "C" void kernel_launch(void* const* d_in, const int* in_sizes, int n_in,
                              void* d_out, int out_size, void* d_ws, size_t ws_size,
                              hipStream_t stream) {
    const float* color  = (const float*)d_in[0];
    const int*   labels = (const int*)d_in[2];
    float* ws  = (float*)d_ws;
    float* out = (float*)d_out;

    int*   spanlab = (int*)ws;
    float* tab     = ws + WS_TAB;
    float* cnt     = ws + WS_CNT;

    // zero only tab+cnt (spanlab is fully overwritten by pass A)
    hipMemsetAsync(tab, 0, (size_t)(TAB_SZ + CNT_SZ) * sizeof(float), stream);

    dim3 gridA(SPANS / 16, NIMG);        // 256 x 8: 16 spans per block
    spanlab_kernel<<<gridA, 256, 0, stream>>>(labels, spanlab);

    dim3 gridB(16, NIMG * NCH);          // 16 chunks x 128 planes = 2048
    stream_kernel<<<gridB, 256, 0, stream>>>(color, labels, spanlab, tab, cnt);

    finalize_kernel<<<1, 256, 0, stream>>>(tab, cnt, out);
}

// Round 9
// 35.853 us; speedup vs baseline: 4.4635x; 1.2005x over previous
//
#include <hip/hip_runtime.h>

// SubtitleColorConsistencyLoss — MI355X (gfx950)
// R8: R1's proven accum body, but labels are pre-compressed to per-span ids
//     (pass A, which also zeroes the global table -> no memset dispatch).
//     Accum reads ONLY color (128 MiB) + 16KB spanlab: no ballot, no label
//     stream, shorter wave prologue. Atomic-cliff lessons respected.

namespace {
constexpr int NIMG = 8;
constexpr int NCH  = 16;
constexpr int HWPX = 512 * 512;
constexpr int KSEG = 65;                 // labels 0..64; slot 0 = background
constexpr int NF   = 18;                 // [0]=count [1]=sqsum [2..17]=sums
constexpr int SPANS = HWPX / 64;         // 4096 spans per image
constexpr int TABF  = NIMG * KSEG * NF;  // 9360 floats
// ws layout: [0, NIMG*SPANS) spanlab ints | [WS_TAB, +TABF) global table
constexpr int WS_TAB = NIMG * SPANS;     // 32768
constexpr float EPSV   = 1e-6f;
constexpr float MARGIN = 0.5f;
constexpr float LAMBDA = 0.4f;
constexpr float MINPIX = 20.0f;
}

// Pass A: span-label compression (uniform 64-px span -> label, else -1)
//         + zero the global table (first 256 blocks, plain stores).
__global__ __launch_bounds__(256) void spanlab_kernel(
    const int* __restrict__ labels, int* __restrict__ spanlab,
    float* __restrict__ tab)
{
    const int n   = blockIdx.y;
    const int tid = threadIdx.x;
    const int grp = tid >> 4, l16 = tid & 15, wgrp = (tid & 63) >> 4;
    const int span = blockIdx.x * 16 + grp;
    const int p    = span * 64 + l16 * 4;

    // zero global table: 256 blocks (image 0) x 37 floats >= 9360
    if (n == 0) {
        if (tid < 37) {
            const int idx = blockIdx.x * 37 + tid;
            if (idx < TABF) tab[idx] = 0.0f;
        }
    }

    const int4 lab = *reinterpret_cast<const int4*>(labels + (size_t)n * HWPX + p);
    const int  lab0 = __shfl(lab.x, 0, 16);
    const bool uni  = (lab.x == lab.y) && (lab.x == lab.z) &&
                      (lab.x == lab.w) && (lab.x == lab0);
    const unsigned long long b = __ballot((int)uni);
    const unsigned long long m = 0xFFFFull << (wgrp * 16);
    if (l16 == 0)
        spanlab[n * SPANS + span] = ((b & m) == m) ? lab0 : -1;
}

__global__ __launch_bounds__(256) void accum_kernel(
    const float* __restrict__ color,
    const int*   __restrict__ labels,
    const int*   __restrict__ spanlab,
    float* __restrict__ tab)
{
    __shared__ float ltab[KSEG * NF];
    const int tid = threadIdx.x;
    for (int i = tid; i < KSEG * NF; i += 256) ltab[i] = 0.0f;
    __syncthreads();

    const int n = blockIdx.y;
    const float* colN = color  + (size_t)n * NCH * HWPX;
    const int*   labN = labels + (size_t)n * HWPX;
    const int*   slN  = spanlab + n * SPANS;

    const int grp = tid >> 4;           // 16-lane group -> one 64-px span
    const int l16 = tid & 15;

    const int stride = gridDim.x * 1024;   // 256 threads * 4 px
    for (int base = blockIdx.x * 1024; base < HWPX; base += stride) {
        const int span = (base >> 6) + grp;
        const int p    = base + grp * 64 + l16 * 4;
        const int slab = slN[span];        // one cached dword per group

        if (slab >= 0) {
            // fast path: uniform span, label known — no label stream at all
            float fs[NCH];
            float sq = 0.0f;
            #pragma unroll
            for (int c = 0; c < NCH; ++c) {
                const float4 v = *reinterpret_cast<const float4*>(
                    colN + (size_t)c * HWPX + p);
                fs[c] = (v.x + v.y) + (v.z + v.w);
                sq += v.x * v.x + v.y * v.y + v.z * v.z + v.w * v.w;
            }
            // reduce-scatter: lane l ends owning channel l's span total
            #pragma unroll
            for (int c = 0; c < 8; ++c) {
                const float snd = (l16 & 8) ? fs[c] : fs[c + 8];
                const float kp  = (l16 & 8) ? fs[c + 8] : fs[c];
                fs[c] = kp + __shfl_xor(snd, 8, 16);
            }
            #pragma unroll
            for (int c = 0; c < 4; ++c) {
                const float snd = (l16 & 4) ? fs[c] : fs[c + 4];
                const float kp  = (l16 & 4) ? fs[c + 4] : fs[c];
                fs[c] = kp + __shfl_xor(snd, 4, 16);
            }
            #pragma unroll
            for (int c = 0; c < 2; ++c) {
                const float snd = (l16 & 2) ? fs[c] : fs[c + 2];
                const float kp  = (l16 & 2) ? fs[c + 2] : fs[c];
                fs[c] = kp + __shfl_xor(snd, 2, 16);
            }
            {
                const float snd = (l16 & 1) ? fs[0] : fs[1];
                const float kp  = (l16 & 1) ? fs[1] : fs[0];
                fs[0] = kp + __shfl_xor(snd, 1, 16);
            }
            sq += __shfl_xor(sq, 8, 16);
            sq += __shfl_xor(sq, 4, 16);
            sq += __shfl_xor(sq, 2, 16);
            sq += __shfl_xor(sq, 1, 16);

            float* seg = ltab + slab * NF;
            atomicAdd(seg + 2 + l16, fs[0]);   // 16 lanes, consecutive addrs
            if (l16 == 0) {
                atomicAdd(seg + 0, 64.0f);
                atomicAdd(seg + 1, sq);
            }
        } else {
            // correctness fallback: per-pixel LDS atomics (never on this data)
            const int4 lb = *reinterpret_cast<const int4*>(labN + p);
            const int labv[4] = {lb.x, lb.y, lb.z, lb.w};
            for (int i = 0; i < 4; ++i) {
                float sqp = 0.0f;
                float* seg = ltab + labv[i] * NF;
                for (int c = 0; c < NCH; ++c) {
                    const float x = colN[(size_t)c * HWPX + p + i];
                    sqp += x * x;
                    atomicAdd(seg + 2 + c, x);
                }
                atomicAdd(seg + 0, 1.0f);
                atomicAdd(seg + 1, sqp);
            }
        }
    }

    __syncthreads();
    // flush (typically 1-2 nonzero segments per block)
    float* tabN = tab + (size_t)n * KSEG * NF;
    for (int i = tid; i < KSEG * NF; i += 256) {
        const float x = ltab[i];
        if (x != 0.0f) atomicAdd(tabN + i, x);
    }
}

__global__ __launch_bounds__(256) void finalize_kernel(
    const float* __restrict__ tab, float* __restrict__ out)
{
    __shared__ float mbg[NIMG][NCH];
    __shared__ float bgcnt[NIMG];
    __shared__ float r0[256], r1[256], r2[256];
    const int tid = threadIdx.x;
    if (tid < NIMG * NCH) {
        const int n = tid / NCH, c = tid % NCH;
        const float* b = tab + (size_t)n * KSEG * NF;   // slot 0 = background
        const float cnt = b[0];
        mbg[n][c] = b[2 + c] / (cnt + EPSV);
        if (c == 0) bgcnt[n] = cnt;
    }
    __syncthreads();

    float vsum = 0.0f, intraS = 0.0f, interS = 0.0f;
    for (int idx = tid; idx < NIMG * KSEG; idx += 256) {
        const int n = idx / KSEG, k = idx % KSEG;
        if (k == 0) continue;
        const float* s = tab + ((size_t)n * KSEG + k) * NF;
        const float cnt = s[0], sq = s[1];
        const float denom = cnt + EPSV;
        float d2 = 0.0f, msf = 0.0f, msm = 0.0f;
        #pragma unroll
        for (int c = 0; c < NCH; ++c) {
            const float f  = s[2 + c];
            const float mu = f / denom;
            msf += mu * f;
            msm += mu * mu;
            const float dd = mu - mbg[n][c];
            d2 += dd * dd;
        }
        const float intra = (sq - 2.0f * msf + cnt * msm) / denom;
        const float dist  = sqrtf(d2 + 1e-12f);
        const float t     = fmaxf(MARGIN - dist, 0.0f);
        const float inter = t * t;
        if ((cnt >= MINPIX) && (bgcnt[n] >= MINPIX)) {
            vsum += 1.0f; intraS += intra; interS += inter;
        }
    }
    r0[tid] = vsum; r1[tid] = intraS; r2[tid] = interS;
    __syncthreads();
    for (int sft = 128; sft; sft >>= 1) {
        if (tid < sft) {
            r0[tid] += r0[tid + sft];
            r1[tid] += r1[tid + sft];
            r2[tid] += r2[tid + sft];
        }
        __syncthreads();
    }
    if (tid == 0) {
        const float total = r0[0];
        const float safe  = fmaxf(total, 1.0f);
        out[0] = (total > 0.0f) ? (r1[0] + LAMBDA * r2[0]) / safe : 0.0f;
    }
}

extern "C" void kernel_launch(void* const* d_in, const int* in_sizes, int n_in,
                              void* d_out, int out_size, void* d_ws, size_t ws_size,
                              hipStream_t stream) {
    const float* color  = (const float*)d_in[0];
    const int*   labels = (const int*)d_in[2];
    float* ws  = (float*)d_ws;
    float* out = (float*)d_out;

    int*   spanlab = (int*)ws;
    float* tab     = ws + WS_TAB;

    dim3 gridA(SPANS / 16, NIMG);    // 256 x 8 blocks; also zeroes tab
    spanlab_kernel<<<gridA, 256, 0, stream>>>(labels, spanlab, tab);

    dim3 gridB(128, NIMG);           // 1024 blocks, grid-stride x2 (R1 proven)
    accum_kernel<<<gridB, 256, 0, stream>>>(color, labels, spanlab, tab);

    finalize_kernel<<<1, 256, 0, stream>>>(tab, out);
}